// Round 19
// baseline (334.137 us; speedup 1.0000x reference)
//
#include <hip/hip_runtime.h>
#include <hip/hip_bf16.h>

#define B_  8
#define D_  256
#define M_  2048
#define DT_ 64
#define KT_ 16
#define UP_ 4
#define NPT (B_ * M_)   // 16384 total points

typedef short bfrag __attribute__((ext_vector_type(8)));   // 8 bf16 (4 VGPRs)
typedef float ffrag __attribute__((ext_vector_type(4)));   // 4 fp32 acc

#define SCL2 0.18033688011112042f   // 0.125 * log2(e), folded into wa2/ba2

static __device__ inline unsigned short f2bf(float x) {
  unsigned int u = __float_as_uint(x);
  unsigned int r = (u + 0x7fffu + ((u >> 16) & 1u)) >> 16;   // RNE
  return (unsigned short)r;
}
static __device__ inline float bf2f(unsigned short u) {
  return __uint_as_float(((unsigned int)u) << 16);
}
static __device__ inline unsigned int cvtpk(float lo, float hi) {
  unsigned int r;
  asm("v_cvt_pk_bf16_f32 %0, %1, %2" : "=v"(r) : "v"(lo), "v"(hi));
  return r;
}
static __device__ inline float fexp2(float x) {
  float r;
  asm("v_exp_f32 %0, %1" : "=v"(r) : "v"(x));
  return r;
}
static __device__ inline float frcp(float x) {
  float r;
  asm("v_rcp_f32 %0, %1" : "=v"(r) : "v"(x));
  return r;
}

__device__ __forceinline__ void gload16(const unsigned short* g, unsigned short* l) {
  __builtin_amdgcn_global_load_lds(
      (const __attribute__((address_space(1))) unsigned int*)(const void*)g,
      (__attribute__((address_space(3))) unsigned int*)(void*)l, 16, 0, 0);
}

// ---------------------------------------------------------------------------
// bf16 MFMA GEMM. Tile: 128 n x 64 o x 64 k (verified round-2..18).
// ---------------------------------------------------------------------------
template<int YOUT, bool RELU, bool SWAP>
__global__ __launch_bounds__(256)
void bgemm_k(const unsigned short* __restrict__ A0, const unsigned short* __restrict__ A1,
             const unsigned short* __restrict__ A2, int ae1, int ae2,
             int lda0, int lda1, int lda2,
             const unsigned short* __restrict__ W0, const unsigned short* __restrict__ W1,
             int be1, int ldw0, int ldw1,
             const float* __restrict__ Bv, void* __restrict__ Yp,
             int IC, int OC, int out_off,
             int azs, int wzs0, int wzs1, int bzs, int ozs, int yzs)
{
  __shared__ unsigned short sX[128 * 64];
  __shared__ unsigned short sW[64 * 64];
  const int z = blockIdx.z;
  A0 += (size_t)z * azs;
  W0 += (size_t)z * wzs0;
  W1 += (size_t)z * wzs1;
  Bv += (size_t)z * bzs;
  out_off += z * ozs;
  unsigned short* Yb = (unsigned short*)Yp + (size_t)z * yzs;
  float*          Yf = (float*)Yp + (size_t)z * yzs;
  const int t    = threadIdx.x;
  const int lane = t & 63, wid = t >> 6;
  const int l15  = lane & 15, lg = lane >> 4;
  const int n0   = blockIdx.x * 128;
  const int o0   = blockIdx.y * 64;
  constexpr int MF = SWAP ? 2 : 4;
  constexpr int NF = SWAP ? 4 : 2;
  const int wa = wid & 1;
  const int wb = wid >> 1;

  ffrag acc[MF][NF];
  #pragma unroll
  for (int mf = 0; mf < MF; ++mf)
    #pragma unroll
    for (int nf = 0; nf < NF; ++nf)
      acc[mf][nf] = (ffrag){0.f, 0.f, 0.f, 0.f};

  for (int k0 = 0; k0 < IC; k0 += 64) {
    const unsigned short* Ap; int lda, ka;
    if (k0 < ae1)      { Ap = A0; lda = lda0; ka = 0;   }
    else if (k0 < ae2) { Ap = A1; lda = lda1; ka = ae1; }
    else               { Ap = A2; lda = lda2; ka = ae2; }
    const unsigned short* Wp; int ldw, kw;
    if (k0 < be1) { Wp = W0; ldw = ldw0; kw = 0;   }
    else          { Wp = W1; ldw = ldw1; kw = be1; }
    #pragma unroll
    for (int it = 0; it < 4; ++it) {
      int idx = it * 256 + t;
      int r = idx >> 3;
      int e = ((idx & 7) * 8) ^ ((r & 7) << 3);
      gload16(Ap + (size_t)(n0 + r) * lda + (k0 - ka) + e, sX + idx * 8);
    }
    #pragma unroll
    for (int it = 0; it < 2; ++it) {
      int idx = it * 256 + t;
      int r = idx >> 3;
      int e = ((idx & 7) * 8) ^ ((r & 7) << 3);
      gload16(Wp + (size_t)(o0 + r) * ldw + (k0 - kw) + e, sW + idx * 8);
    }
    __syncthreads();
    bfrag af[MF][2], bfr[NF][2];
    #pragma unroll
    for (int mf = 0; mf < MF; ++mf)
      #pragma unroll
      for (int kf = 0; kf < 2; ++kf) {
        int r = SWAP ? (wa * 32 + mf * 16 + l15) : (wa * 64 + mf * 16 + l15);
        int e = (kf * 32 + lg * 8) ^ ((r & 7) << 3);
        af[mf][kf] = *reinterpret_cast<const bfrag*>((SWAP ? sW : sX) + r * 64 + e);
      }
    #pragma unroll
    for (int nf = 0; nf < NF; ++nf)
      #pragma unroll
      for (int kf = 0; kf < 2; ++kf) {
        int r = SWAP ? (wb * 64 + nf * 16 + l15) : (wb * 32 + nf * 16 + l15);
        int e = (kf * 32 + lg * 8) ^ ((r & 7) << 3);
        bfr[nf][kf] = *reinterpret_cast<const bfrag*>((SWAP ? sX : sW) + r * 64 + e);
      }
    #pragma unroll
    for (int kf = 0; kf < 2; ++kf)
      #pragma unroll
      for (int mf = 0; mf < MF; ++mf)
        #pragma unroll
        for (int nf = 0; nf < NF; ++nf)
          acc[mf][nf] = __builtin_amdgcn_mfma_f32_16x16x32_bf16(
              af[mf][kf], bfr[nf][kf], acc[mf][nf], 0, 0, 0);
    __syncthreads();
  }

  if (!SWAP) {
    #pragma unroll
    for (int mf = 0; mf < MF; ++mf) {
      int n = n0 + wa * 64 + mf * 16 + lg * 4;
      #pragma unroll
      for (int nf = 0; nf < NF; ++nf) {
        int o = o0 + wb * 32 + nf * 16 + l15;
        float bias = Bv[o];
        #pragma unroll
        for (int i = 0; i < 4; ++i) {
          float v = acc[mf][nf][i] + bias;
          if (RELU) v = fmaxf(v, 0.f);
          size_t yi = (size_t)(n + i) * OC + o;
          if (YOUT == 0) Yb[yi] = f2bf(v);
          else           Yf[yi] = v;
        }
      }
    }
  } else {
    #pragma unroll
    for (int mf = 0; mf < MF; ++mf)
      #pragma unroll
      for (int i = 0; i < 4; ++i) {
        int o = o0 + wa * 32 + mf * 16 + lg * 4 + i;
        float bias = Bv[o];
        #pragma unroll
        for (int nf = 0; nf < NF; ++nf) {
          int n = n0 + wb * 64 + nf * 16 + l15;
          float v = acc[mf][nf][i] + bias;
          int b = n >> 11, m = n & 2047;
          Yf[((size_t)b * 256 + o) * 8192 + out_off + m] = v;
        }
      }
  }
}

// ---------------------------------------------------------------------------
// FRONT kernel (r18-verified fusion): knn [0,2048) + cvtT [2048,4096) +
// wcvt [4096,7383). r19 delta: knn rescan restructured into 4 independent
// partial min-chains per query (depth 8 instead of 32) + lexicographic
// (d, nn) merge — EXACT same winner as the sequential scan (min d, lowest
// nn on ties). 8 independent chains/wave total (2 queries x 4 chains).
// ---------------------------------------------------------------------------
__global__ __launch_bounds__(256)
void front_k(const float* __restrict__ xyz, int* __restrict__ ids,
             const float* __restrict__ wp1, const float* __restrict__ bp1,
             unsigned short* __restrict__ t1,
             const float* __restrict__ fq, const float* __restrict__ fk,
             unsigned short* __restrict__ xqb, unsigned short* __restrict__ xkb,
             const float* __restrict__ w1, const float* __restrict__ w2,
             const float* __restrict__ wres, const float* __restrict__ wq,
             const float* __restrict__ wk, const float* __restrict__ wv,
             const float* __restrict__ wo, const float* __restrict__ wr,
             const float* __restrict__ wa1, const float* __restrict__ wa2,
             const float* __restrict__ wp2,
             const float* __restrict__ bo, const float* __restrict__ br,
             const float* __restrict__ b2, const float* __restrict__ bres,
             const float* __restrict__ bq, const float* __restrict__ bk,
             const float* __restrict__ bv, const float* __restrict__ ba2,
             unsigned short* __restrict__ wreg, float* __restrict__ bsum)
{
  __shared__ float smem[6528];   // 25.5 KB union: knn(sx,sy,sz,wp1,bp1,qid) / cvtT(sT)
  const int id = blockIdx.x;
  const int t  = threadIdx.x;

  if (id < 2048) {
    // ---------------- knn branch ----------------
    float* sx = smem;
    float* sy = smem + 2048;
    float* sz = smem + 4096;
    float* s_wp1 = smem + 6144;            // 192
    float* s_bp1 = smem + 6336;            // 64
    int*   s_qid = (int*)(smem + 6400);    // 128 ints
    const int b  = id >> 8;
    const int mg = id & 255;
    const float* xb = xyz + (size_t)b * 2048 * 3;
    for (int i = t; i < 2048; i += 256) {
      float x = xb[3 * i], y = xb[3 * i + 1], z = xb[3 * i + 2];
      sx[i] = x; sy[i] = y; sz[i] = z;
    }
    if (t < 192) s_wp1[t] = wp1[t];
    if (t < 64)  s_bp1[t] = bp1[t];
    __syncthreads();
    const int wave = t >> 6, lane = t & 63;
    const int m0 = mg * 8 + wave * 2;
    const int m1 = m0 + 1;
    const float xm0 = sx[m0], ym0 = sy[m0], zm0 = sz[m0];
    const float xm1 = sx[m1], ym1 = sy[m1], zm1 = sz[m1];
    const float sq0 = xm0 * xm0 + ym0 * ym0 + zm0 * zm0;
    const float sq1 = xm1 * xm1 + ym1 * ym1 + zm1 * zm1;

    float d0[32], d1[32];
    #pragma unroll
    for (int j = 0; j < 32; ++j) {
      int nn = lane + 64 * j;
      float px = sx[nn], py = sy[nn], pz = sz[nn];
      float ps = px * px + py * py + pz * pz;
      d0[j] = sq0 + ps - 2.f * (px * xm0 + py * ym0 + pz * zm0);
      d1[j] = sq1 + ps - 2.f * (px * xm1 + py * ym1 + pz * zm1);
    }
    int* outp0 = ids + ((size_t)b * 2048 + m0) * 16;
    int* outp1 = ids + ((size_t)b * 2048 + m1) * 16;

    for (int it = 0; it < 16; ++it) {
      // 4 independent partial min-chains per query (depth 8), exact lex-min
      float c0d0 = 3.4e38f, c0d1 = 3.4e38f, c0d2 = 3.4e38f, c0d3 = 3.4e38f;
      int   c0n0 = 0x7fffffff, c0n1 = 0x7fffffff, c0n2 = 0x7fffffff, c0n3 = 0x7fffffff;
      float c1d0 = 3.4e38f, c1d1 = 3.4e38f, c1d2 = 3.4e38f, c1d3 = 3.4e38f;
      int   c1n0 = 0x7fffffff, c1n1 = 0x7fffffff, c1n2 = 0x7fffffff, c1n3 = 0x7fffffff;
      #pragma unroll
      for (int j = 0; j < 32; j += 4) {
        int nn = lane + 64 * j;
        if (d0[j]     < c0d0) { c0d0 = d0[j];     c0n0 = nn;       }
        if (d0[j + 1] < c0d1) { c0d1 = d0[j + 1]; c0n1 = nn + 64;  }
        if (d0[j + 2] < c0d2) { c0d2 = d0[j + 2]; c0n2 = nn + 128; }
        if (d0[j + 3] < c0d3) { c0d3 = d0[j + 3]; c0n3 = nn + 192; }
        if (d1[j]     < c1d0) { c1d0 = d1[j];     c1n0 = nn;       }
        if (d1[j + 1] < c1d1) { c1d1 = d1[j + 1]; c1n1 = nn + 64;  }
        if (d1[j + 2] < c1d2) { c1d2 = d1[j + 2]; c1n2 = nn + 128; }
        if (d1[j + 3] < c1d3) { c1d3 = d1[j + 3]; c1n3 = nn + 192; }
      }
      // lex merge (d, nn): chain pairs, then final
      if (c0d1 < c0d0 || (c0d1 == c0d0 && c0n1 < c0n0)) { c0d0 = c0d1; c0n0 = c0n1; }
      if (c0d3 < c0d2 || (c0d3 == c0d2 && c0n3 < c0n2)) { c0d2 = c0d3; c0n2 = c0n3; }
      if (c1d1 < c1d0 || (c1d1 == c1d0 && c1n1 < c1n0)) { c1d0 = c1d1; c1n0 = c1n1; }
      if (c1d3 < c1d2 || (c1d3 == c1d2 && c1n3 < c1n2)) { c1d2 = c1d3; c1n2 = c1n3; }
      float bd0 = c0d0; int bn0 = c0n0;
      if (c0d2 < bd0 || (c0d2 == bd0 && c0n2 < bn0)) { bd0 = c0d2; bn0 = c0n2; }
      float bd1 = c1d0; int bn1 = c1n0;
      if (c1d2 < bd1 || (c1d2 == bd1 && c1n2 < bn1)) { bd1 = c1d2; bn1 = c1n2; }

      #pragma unroll
      for (int off = 32; off > 0; off >>= 1) {
        float od0 = __shfl_xor(bd0, off, 64);
        int   on0 = __shfl_xor(bn0, off, 64);
        float od1 = __shfl_xor(bd1, off, 64);
        int   on1 = __shfl_xor(bn1, off, 64);
        if (od0 < bd0 || (od0 == bd0 && on0 < bn0)) { bd0 = od0; bn0 = on0; }
        if (od1 < bd1 || (od1 == bd1 && on1 < bn1)) { bd1 = od1; bn1 = on1; }
      }
      if ((bn0 & 63) == lane) {
        #pragma unroll
        for (int j = 0; j < 32; ++j) if (j == (bn0 >> 6)) d0[j] = 3.4e38f;
      }
      if ((bn1 & 63) == lane) {
        #pragma unroll
        for (int j = 0; j < 32; ++j) if (j == (bn1 >> 6)) d1[j] = 3.4e38f;
      }
      if (lane == 0) {
        outp0[it] = bn0; s_qid[wave * 32 + it] = bn0;
        outp1[it] = bn1; s_qid[wave * 32 + 16 + it] = bn1;
      }
    }

    float w0 = s_wp1[lane * 3 + 0], w1v = s_wp1[lane * 3 + 1], w2v = s_wp1[lane * 3 + 2];
    float bb = s_bp1[lane];
    {
      unsigned short* t1p = t1 + (((size_t)b * 2048 + m0) * 16) * 64;
      #pragma unroll
      for (int nb = 0; nb < 16; ++nb) {
        int idn = s_qid[wave * 32 + nb];
        float dx = sx[idn] - xm0, dy = sy[idn] - ym0, dz = sz[idn] - zm0;
        float v = fmaxf(w0 * dx + w1v * dy + w2v * dz + bb, 0.f);
        t1p[nb * 64 + lane] = f2bf(v);
      }
    }
    {
      unsigned short* t1p = t1 + (((size_t)b * 2048 + m1) * 16) * 64;
      #pragma unroll
      for (int nb = 0; nb < 16; ++nb) {
        int idn = s_qid[wave * 32 + 16 + nb];
        float dx = sx[idn] - xm1, dy = sy[idn] - ym1, dz = sz[idn] - zm1;
        float v = fmaxf(w0 * dx + w1v * dy + w2v * dz + bb, 0.f);
        t1p[nb * 64 + lane] = f2bf(v);
      }
    }
  } else if (id < 4096) {
    // ---------------- cvtT branch ----------------
    unsigned short* sT = (unsigned short*)smem;    // [64][68]
    const int lid = id - 2048;
    const int m0 = (lid & 31) * 64;
    const int c0 = ((lid >> 5) & 3) * 64;
    const int z  = lid >> 7;
    const int b  = z >> 1;
    const float* src = (z & 1) ? fk : fq;
    unsigned short* dst = (z & 1) ? xkb : xqb;
    #pragma unroll
    for (int it = 0; it < 16; ++it) {
      int idx = it * 256 + t;
      int c = idx >> 6, m = idx & 63;
      sT[m * 68 + c] = f2bf(src[((size_t)b * 256 + c0 + c) * 2048 + m0 + m]);
    }
    __syncthreads();
    #pragma unroll
    for (int it = 0; it < 8; ++it) {
      int idx = it * 256 + t;
      int n = idx >> 5, cw = idx & 31;
      unsigned int w = *reinterpret_cast<const unsigned int*>(&sT[n * 68 + cw * 2]);
      *reinterpret_cast<unsigned int*>(&dst[((size_t)b * 2048 + m0 + n) * 256 + c0 + cw * 2]) = w;
    }
  } else {
    // ---------------- weight-convert branch ----------------
    int i = (id - 4096) * 256 + t;
    if      (i < 131072) wreg[i] = f2bf(w1[i]);
    else if (i < 196608) wreg[i] = f2bf(w2[i - 131072]);
    else if (i < 327680) wreg[i] = f2bf(wres[i - 196608]);
    else if (i < 344064) wreg[i] = f2bf(wq[i - 327680]);
    else if (i < 360448) wreg[i] = f2bf(wk[i - 344064]);
    else if (i < 376832) wreg[i] = f2bf(wv[i - 360448]);
    else if (i < 442368) wreg[i] = f2bf(wo[i - 376832]);
    else if (i < 704512) wreg[i] = f2bf(wr[i - 442368]);
    else if (i < 770048) wreg[i] = f2bf(wa1[i - 704512]);
    else if (i < 835584) wreg[i] = f2bf(wa2[i - 770048] * SCL2);
    else if (i < 839680) wreg[i] = f2bf(wp2[i - 835584]);
    else {
      int j = i - 839680;
      if (j < 1024)      bsum[j] = bo[j] + br[j];
      else if (j < 1280) bsum[j] = b2[j - 1024] + bres[j - 1024];
      else if (j < 1472) {
        int j2 = j - 1280, zz = j2 >> 6, o = j2 & 63;
        bsum[j] = (zz == 0) ? bq[o] : (zz == 1) ? bk[o] : bv[o];
      }
      else if (j < 1728) bsum[j] = ba2[j - 1472] * SCL2;
    }
  }
}

// ---------------------------------------------------------------------------
// prep2: gather + assemble a0 = q - k_nbr + pos, vp = v_nbr + pos (bf16)
// ---------------------------------------------------------------------------
__global__ __launch_bounds__(256)
void prep2_k(const unsigned short* __restrict__ qb, const unsigned short* __restrict__ kb,
             const unsigned short* __restrict__ vb, const int* __restrict__ idsp,
             const unsigned short* __restrict__ posb,
             unsigned short* __restrict__ a0g, unsigned short* __restrict__ vpg)
{
  const int n = blockIdx.x;
  const int b = n >> 11;
  const int t = threadIdx.x;
  __shared__ int s_id[16];
  if (t < 16) s_id[t] = idsp[(size_t)n * 16 + t];
  __syncthreads();
  const int k  = t >> 4;
  const int c0 = (t & 15) * 4;
  const int nb = s_id[k];
  size_t colb = ((size_t)n * 16 + k) * 64 + c0;
  ushort4 q4 = *reinterpret_cast<const ushort4*>(qb + (size_t)n * 64 + c0);
  ushort4 k4 = *reinterpret_cast<const ushort4*>(kb + ((size_t)b * 2048 + nb) * 64 + c0);
  ushort4 v4 = *reinterpret_cast<const ushort4*>(vb + ((size_t)b * 2048 + nb) * 64 + c0);
  ushort4 p4 = *reinterpret_cast<const ushort4*>(posb + colb);
  float p0 = bf2f(p4.x), p1 = bf2f(p4.y), p2 = bf2f(p4.z), p3 = bf2f(p4.w);
  ushort4 av, wv;
  av.x = f2bf(bf2f(q4.x) - bf2f(k4.x) + p0);
  av.y = f2bf(bf2f(q4.y) - bf2f(k4.y) + p1);
  av.z = f2bf(bf2f(q4.z) - bf2f(k4.z) + p2);
  av.w = f2bf(bf2f(q4.w) - bf2f(k4.w) + p3);
  wv.x = f2bf(bf2f(v4.x) + p0);
  wv.y = f2bf(bf2f(v4.y) + p1);
  wv.z = f2bf(bf2f(v4.z) + p2);
  wv.w = f2bf(bf2f(v4.w) + p3);
  *reinterpret_cast<ushort4*>(a0g + colb) = av;
  *reinterpret_cast<ushort4*>(vpg + colb) = wv;
}

// ---------------------------------------------------------------------------
// MFMA attention v9 (r15/r17/r18-verified): XCD swizzle, W-in-LDS, VALU diet.
// ---------------------------------------------------------------------------
__global__ __launch_bounds__(256)
void attn_mfma_k(const unsigned short* __restrict__ a0g,
                 const unsigned short* __restrict__ vpg,
                 const unsigned short* __restrict__ w1bf,
                 const unsigned short* __restrict__ w2bf,
                 const float* __restrict__ ba1, const float* __restrict__ ba2s,
                 unsigned short* __restrict__ fb)
{
  const int bid  = blockIdx.x;
  const int up   = (bid >> 3) & 3;
  const int xblk = ((bid >> 5) << 3) + (bid & 7);
  const int wid  = threadIdx.x >> 6;
  const int lane = threadIdx.x & 63;
  const int l15  = lane & 15;
  const int lg   = lane >> 4;
  const int m0   = xblk * 256 + wid * 64;

  __shared__ unsigned short sW1[16384];
  __shared__ unsigned short sW2[16384];

  const unsigned short* W1 = w1bf + up * 16384;
  const unsigned short* W2 = w2bf + up * 16384;
  const float* B1 = ba1 + up * 256;
  const float* B2 = ba2s + up * 64;

  #pragma unroll
  for (int it = 0; it < 8; ++it) {
    int idx = it * 256 + threadIdx.x;
    int r = idx >> 3;
    int e = ((idx & 7) * 8) ^ ((r & 7) << 3);
    gload16(W1 + r * 64 + e, sW1 + idx * 8);
  }
  #pragma unroll
  for (int it = 0; it < 8; ++it) {
    int idx = it * 256 + threadIdx.x;
    int r = idx >> 3;
    int e = ((idx & 7) * 8) ^ ((r & 7) << 3);
    gload16(W2 + r * 64 + e, sW2 + idx * 8);
  }

  bfrag bf[4][2];
  #pragma unroll
  for (int nfc = 0; nfc < 4; ++nfc)
    #pragma unroll
    for (int kf = 0; kf < 2; ++kf)
      bf[nfc][kf] = *reinterpret_cast<const bfrag*>(
          a0g + (size_t)(m0 + nfc * 16 + l15) * 64 + kf * 32 + lg * 8);

  ffrag acc2[4][4];
  #pragma unroll
  for (int mf = 0; mf < 4; ++mf)
    #pragma unroll
    for (int nf = 0; nf < 4; ++nf)
      acc2[mf][nf] = (ffrag){0.f, 0.f, 0.f, 0.f};

  __syncthreads();

  const int orow_base = ((l15 >> 2) << 3) + (l15 & 3);

  for (int oc = 0; oc < 8; ++oc) {
    bfrag w1p[2][2];
    #pragma unroll
    for (int p = 0; p < 2; ++p)
      #pragma unroll
      for (int kf = 0; kf < 2; ++kf) {
        int r = oc * 32 + orow_base + 4 * p;
        int off = (kf * 32 + lg * 8) ^ ((r & 7) << 3);
        w1p[p][kf] = *reinterpret_cast<const bfrag*>(sW1 + r * 64 + off);
      }
    float4 b1q[2];
    #pragma unroll
    for (int p = 0; p < 2; ++p)
      b1q[p] = *reinterpret_cast<const float4*>(B1 + oc * 32 + lg * 8 + 4 * p);

    ffrag acc1[2][4];
    #pragma unroll
    for (int p = 0; p < 2; ++p)
      #pragma unroll
      for (int nfc = 0; nfc < 4; ++nfc)
        acc1[p][nfc] = (ffrag){b1q[p].x, b1q[p].y, b1q[p].z, b1q[p].w};
    #pragma unroll
    for (int kf = 0; kf < 2; ++kf)
      #pragma unroll
      for (int p = 0; p < 2; ++p)
        #pragma unroll
        for (int nfc = 0; nfc < 4; ++nfc)
          acc1[p][nfc] = __builtin_amdgcn_mfma_f32_16x16x32_bf16(
              w1p[p][kf], bf[nfc][kf], acc1[p][nfc], 0, 0, 0);

    bfrag w2t[4];
    #pragma unroll
    for (int nfd = 0; nfd < 4; ++nfd) {
      int dt = nfd * 16 + l15;
      int sr = dt * 4 + (oc >> 1);
      int off = ((oc & 1) * 32 + lg * 8) ^ ((sr & 7) << 3);
      w2t[nfd] = *reinterpret_cast<const bfrag*>(sW2 + sr * 64 + off);
    }

    #pragma unroll
    for (int nfc = 0; nfc < 4; ++nfc) {
      union { unsigned int u[4]; bfrag v; } cv;
      cv.u[0] = cvtpk(fmaxf(acc1[0][nfc][0], 0.f), fmaxf(acc1[0][nfc][1], 0.f));
      cv.u[1] = cvtpk(fmaxf(acc1[0][nfc][2], 0.f), fmaxf(acc1[0][nfc][3], 0.f));
      cv.u[2] = cvtpk(fmaxf(acc1[1][nfc][0], 0.f), fmaxf(acc1[1][nfc][1], 0.f));
      cv.u[3] = cvtpk(fmaxf(acc1[1][nfc][2], 0.f), fmaxf(acc1[1][nfc][3], 0.f));
      #pragma unroll
      for (int nfd = 0; nfd < 4; ++nfd)
        acc2[nfc][nfd] = __builtin_amdgcn_mfma_f32_16x16x32_bf16(
            cv.v, w2t[nfd], acc2[nfc][nfd], 0, 0, 0);
    }
  }

  #pragma unroll
  for (int mf = 0; mf < 4; ++mf) {
    float fsel = 0.f;
    #pragma unroll
    for (int nf = 0; nf < 4; ++nf) {
      float b2v = B2[nf * 16 + l15];
      float e[4], s = 0.f;
      #pragma unroll
      for (int i = 0; i < 4; ++i) { e[i] = fexp2(acc2[mf][nf][i] + b2v); s += e[i]; }
      s += __shfl_xor(s, 16, 64);
      s += __shfl_xor(s, 32, 64);
      float inv = frcp(s);
      float fp = 0.f;
      #pragma unroll
      for (int i = 0; i < 4; ++i) {
        int col = m0 + mf * 16 + lg * 4 + i;
        float vpv = bf2f(vpg[(size_t)col * 64 + nf * 16 + l15]);
        fp = fmaf(e[i] * inv, vpv, fp);
      }
      fp += __shfl_xor(fp, 16, 64);
      fp += __shfl_xor(fp, 32, 64);
      if (lg == nf) fsel = fp;
    }
    int pt = xblk * 16 + wid * 4 + mf;
    fb[((size_t)up * NPT + pt) * 64 + lane] = f2bf(fsel);
  }
}

// ---------------------------------------------------------------------------
extern "C" void kernel_launch(void* const* d_in, const int* in_sizes, int n_in,
                              void* d_out, int out_size, void* d_ws, size_t ws_size,
                              hipStream_t stream)
{
  const float* fq   = (const float*)d_in[0];
  const float* fk   = (const float*)d_in[1];
  const float* xyz  = (const float*)d_in[2];
  const float* w1   = (const float*)d_in[3];
  const float* b1   = (const float*)d_in[4];
  const float* w2   = (const float*)d_in[5];
  const float* b2   = (const float*)d_in[6];
  const float* wres = (const float*)d_in[7];
  const float* bres = (const float*)d_in[8];
  const float* wq   = (const float*)d_in[9];
  const float* bq   = (const float*)d_in[10];
  const float* wk   = (const float*)d_in[11];
  const float* bk   = (const float*)d_in[12];
  const float* wv   = (const float*)d_in[13];
  const float* bv   = (const float*)d_in[14];
  const float* wp1  = (const float*)d_in[15];
  const float* bp1  = (const float*)d_in[16];
  const float* wp2  = (const float*)d_in[17];
  const float* bp2  = (const float*)d_in[18];
  const float* wa1  = (const float*)d_in[19];
  const float* ba1  = (const float*)d_in[20];
  const float* wa2  = (const float*)d_in[21];
  const float* ba2  = (const float*)d_in[22];
  const float* wo   = (const float*)d_in[23];
  const float* bo   = (const float*)d_in[24];
  const float* wr   = (const float*)d_in[25];
  const float* br   = (const float*)d_in[26];
  float* out = (float*)d_out;
  (void)in_sizes; (void)n_in; (void)out_size; (void)ws_size;

  unsigned short* u    = (unsigned short*)d_ws;
  unsigned short* wreg = u;                        //   839,680
  unsigned short* xqb  = wreg + 839680;            // 4,194,304
  unsigned short* xkb  = xqb  + 4194304;
  unsigned short* ftsb = xkb  + 4194304;
  unsigned short* h1b  = ftsb + 4194304;           // reused as fbb
  unsigned short* a0g  = h1b  + 4194304;           // 16,777,216 (aliases t1)
  unsigned short* vpg  = a0g  + 16777216;          // 16,777,216 (aliases posb)
  unsigned short* qb   = vpg  + 16777216;          // 1,048,576
  unsigned short* kb   = qb   + 1048576;
  unsigned short* vb   = kb   + 1048576;
  int*   ids  = (int*)(vb + 1048576);              // 262,144 ints
  float* bsum = (float*)(ids + 262144);            // 1,728 floats

  unsigned short* w1b   = wreg;
  unsigned short* w2b   = wreg + 131072;
  unsigned short* wresb = wreg + 196608;
  unsigned short* wqb   = wreg + 327680;
  unsigned short* wrb   = wreg + 442368;
  unsigned short* wob   = wreg + 376832;
  unsigned short* wa1b  = wreg + 704512;
  unsigned short* wa2b  = wreg + 770048;
  unsigned short* wp2b  = wreg + 835584;
  unsigned short* t1    = a0g;    // alias: t1 dead before a0g written
  unsigned short* posb  = vpg;    // alias: consumed in place by prep2
  unsigned short* fbb   = h1b;
  const int BIG = 1 << 30;

  dim3 blk(256);

  // fused front: knn (blocks 0..2047) + cvtT (2048..4095) + wcvt (4096..7382)
  front_k<<<dim3(7383), blk, 0, stream>>>(
      xyz, ids, wp1, bp1, t1,
      fq, fk, xqb, xkb,
      w1, w2, wres, wq, wk, wv, wo, wr, wa1, wa2, wp2,
      bo, br, b2, bres, bq, bk, bv, ba2, wreg, bsum);

  // h1 = relu(w1 @ [fq;fk] + b1)  -> bf16 [n][256]
  bgemm_k<0, true, false><<<dim3(128, 4), blk, 0, stream>>>(
      xqb, xkb, xkb, 256, BIG, 256, 256, 256,
      w1b, w1b, BIG, 512, 512, b1, h1b, 512, 256, 0, 0, 0, 0, 0, 0, 0);
  // ftsv = [w2|wres] @ [h1;fq;fk] + (b2+bres) -> bf16 [n][256]
  bgemm_k<0, false, false><<<dim3(128, 4), blk, 0, stream>>>(
      h1b, xqb, xkb, 256, 512, 256, 256, 256,
      w2b, wresb, 256, 256, 512, bsum + 1024, ftsb, 768, 256, 0, 0, 0, 0, 0, 0, 0);
  // q, k, v projections fused: z = 0,1,2 over {xqb,xkb,ftsb} x {wq,wk,wv}
  bgemm_k<0, false, false><<<dim3(128, 1, 3), blk, 0, stream>>>(
      xqb, xqb, xqb, BIG, BIG, 256, 256, 256,
      wqb, wqb, BIG, 256, 256, bsum + 1280, qb, 256, 64, 0,
      4194304, 16384, 16384, 64, 0, 1048576);

  // pos = wp2 @ t1 + bp2  -> bf16 [col][64]   (N = 262144 cols)
  bgemm_k<0, false, false><<<dim3(2048, 1), blk, 0, stream>>>(
      t1, t1, t1, BIG, BIG, 64, 64, 64,
      wp2b, wp2b, BIG, 64, 64, bp2, posb, 64, 64, 0, 0, 0, 0, 0, 0, 0);

  prep2_k<<<dim3(NPT), blk, 0, stream>>>(qb, kb, vb, ids, posb, a0g, vpg);
  attn_mfma_k<<<dim3(4096), blk, 0, stream>>>(a0g, vpg, wa1b, wa2b, ba1, bsum + 1472, fbb);

  // out[:, :, i*2048:(i+1)*2048] = [wo_i|wr_i] @ [f_i; ftsv] + (bo_i+br_i)
  bgemm_k<2, false, true><<<dim3(128, 4, UP_), blk, 0, stream>>>(
      fbb, ftsb, ftsb, 64, BIG, 64, 256, 256,
      wob, wrb, 64, 64, 256,
      bsum, out, 320, 256, 0,
      1048576, 16384, 65536, 256, 2048, 0);
}

// Round 20
// 321.773 us; speedup vs baseline: 1.0384x; 1.0384x over previous
//
#include <hip/hip_runtime.h>
#include <hip/hip_bf16.h>

#define B_  8
#define D_  256
#define M_  2048
#define DT_ 64
#define KT_ 16
#define UP_ 4
#define NPT (B_ * M_)   // 16384 total points

typedef short bfrag __attribute__((ext_vector_type(8)));   // 8 bf16 (4 VGPRs)
typedef float ffrag __attribute__((ext_vector_type(4)));   // 4 fp32 acc

#define SCL2 0.18033688011112042f   // 0.125 * log2(e), folded into wa2/ba2

static __device__ inline unsigned short f2bf(float x) {
  unsigned int u = __float_as_uint(x);
  unsigned int r = (u + 0x7fffu + ((u >> 16) & 1u)) >> 16;   // RNE
  return (unsigned short)r;
}
static __device__ inline float bf2f(unsigned short u) {
  return __uint_as_float(((unsigned int)u) << 16);
}
static __device__ inline unsigned int cvtpk(float lo, float hi) {
  unsigned int r;
  asm("v_cvt_pk_bf16_f32 %0, %1, %2" : "=v"(r) : "v"(lo), "v"(hi));
  return r;
}
static __device__ inline float fexp2(float x) {
  float r;
  asm("v_exp_f32 %0, %1" : "=v"(r) : "v"(x));
  return r;
}
static __device__ inline float frcp(float x) {
  float r;
  asm("v_rcp_f32 %0, %1" : "=v"(r) : "v"(x));
  return r;
}

__device__ __forceinline__ void gload16(const unsigned short* g, unsigned short* l) {
  __builtin_amdgcn_global_load_lds(
      (const __attribute__((address_space(1))) unsigned int*)(const void*)g,
      (__attribute__((address_space(3))) unsigned int*)(void*)l, 16, 0, 0);
}

// ---------------------------------------------------------------------------
// bf16 MFMA GEMM. Tile: 128 n x 64 o x 64 k (verified round-2..18).
// ---------------------------------------------------------------------------
template<int YOUT, bool RELU, bool SWAP>
__global__ __launch_bounds__(256)
void bgemm_k(const unsigned short* __restrict__ A0, const unsigned short* __restrict__ A1,
             const unsigned short* __restrict__ A2, int ae1, int ae2,
             int lda0, int lda1, int lda2,
             const unsigned short* __restrict__ W0, const unsigned short* __restrict__ W1,
             int be1, int ldw0, int ldw1,
             const float* __restrict__ Bv, void* __restrict__ Yp,
             int IC, int OC, int out_off,
             int azs, int wzs0, int wzs1, int bzs, int ozs, int yzs)
{
  __shared__ unsigned short sX[128 * 64];
  __shared__ unsigned short sW[64 * 64];
  const int z = blockIdx.z;
  A0 += (size_t)z * azs;
  W0 += (size_t)z * wzs0;
  W1 += (size_t)z * wzs1;
  Bv += (size_t)z * bzs;
  out_off += z * ozs;
  unsigned short* Yb = (unsigned short*)Yp + (size_t)z * yzs;
  float*          Yf = (float*)Yp + (size_t)z * yzs;
  const int t    = threadIdx.x;
  const int lane = t & 63, wid = t >> 6;
  const int l15  = lane & 15, lg = lane >> 4;
  const int n0   = blockIdx.x * 128;
  const int o0   = blockIdx.y * 64;
  constexpr int MF = SWAP ? 2 : 4;
  constexpr int NF = SWAP ? 4 : 2;
  const int wa = wid & 1;
  const int wb = wid >> 1;

  ffrag acc[MF][NF];
  #pragma unroll
  for (int mf = 0; mf < MF; ++mf)
    #pragma unroll
    for (int nf = 0; nf < NF; ++nf)
      acc[mf][nf] = (ffrag){0.f, 0.f, 0.f, 0.f};

  for (int k0 = 0; k0 < IC; k0 += 64) {
    const unsigned short* Ap; int lda, ka;
    if (k0 < ae1)      { Ap = A0; lda = lda0; ka = 0;   }
    else if (k0 < ae2) { Ap = A1; lda = lda1; ka = ae1; }
    else               { Ap = A2; lda = lda2; ka = ae2; }
    const unsigned short* Wp; int ldw, kw;
    if (k0 < be1) { Wp = W0; ldw = ldw0; kw = 0;   }
    else          { Wp = W1; ldw = ldw1; kw = be1; }
    #pragma unroll
    for (int it = 0; it < 4; ++it) {
      int idx = it * 256 + t;
      int r = idx >> 3;
      int e = ((idx & 7) * 8) ^ ((r & 7) << 3);
      gload16(Ap + (size_t)(n0 + r) * lda + (k0 - ka) + e, sX + idx * 8);
    }
    #pragma unroll
    for (int it = 0; it < 2; ++it) {
      int idx = it * 256 + t;
      int r = idx >> 3;
      int e = ((idx & 7) * 8) ^ ((r & 7) << 3);
      gload16(Wp + (size_t)(o0 + r) * ldw + (k0 - kw) + e, sW + idx * 8);
    }
    __syncthreads();
    bfrag af[MF][2], bfr[NF][2];
    #pragma unroll
    for (int mf = 0; mf < MF; ++mf)
      #pragma unroll
      for (int kf = 0; kf < 2; ++kf) {
        int r = SWAP ? (wa * 32 + mf * 16 + l15) : (wa * 64 + mf * 16 + l15);
        int e = (kf * 32 + lg * 8) ^ ((r & 7) << 3);
        af[mf][kf] = *reinterpret_cast<const bfrag*>((SWAP ? sW : sX) + r * 64 + e);
      }
    #pragma unroll
    for (int nf = 0; nf < NF; ++nf)
      #pragma unroll
      for (int kf = 0; kf < 2; ++kf) {
        int r = SWAP ? (wb * 64 + nf * 16 + l15) : (wb * 32 + nf * 16 + l15);
        int e = (kf * 32 + lg * 8) ^ ((r & 7) << 3);
        bfr[nf][kf] = *reinterpret_cast<const bfrag*>((SWAP ? sX : sW) + r * 64 + e);
      }
    #pragma unroll
    for (int kf = 0; kf < 2; ++kf)
      #pragma unroll
      for (int mf = 0; mf < MF; ++mf)
        #pragma unroll
        for (int nf = 0; nf < NF; ++nf)
          acc[mf][nf] = __builtin_amdgcn_mfma_f32_16x16x32_bf16(
              af[mf][kf], bfr[nf][kf], acc[mf][nf], 0, 0, 0);
    __syncthreads();
  }

  if (!SWAP) {
    #pragma unroll
    for (int mf = 0; mf < MF; ++mf) {
      int n = n0 + wa * 64 + mf * 16 + lg * 4;
      #pragma unroll
      for (int nf = 0; nf < NF; ++nf) {
        int o = o0 + wb * 32 + nf * 16 + l15;
        float bias = Bv[o];
        #pragma unroll
        for (int i = 0; i < 4; ++i) {
          float v = acc[mf][nf][i] + bias;
          if (RELU) v = fmaxf(v, 0.f);
          size_t yi = (size_t)(n + i) * OC + o;
          if (YOUT == 0) Yb[yi] = f2bf(v);
          else           Yf[yi] = v;
        }
      }
    }
  } else {
    #pragma unroll
    for (int mf = 0; mf < MF; ++mf)
      #pragma unroll
      for (int i = 0; i < 4; ++i) {
        int o = o0 + wa * 32 + mf * 16 + lg * 4 + i;
        float bias = Bv[o];
        #pragma unroll
        for (int nf = 0; nf < NF; ++nf) {
          int n = n0 + wb * 64 + nf * 16 + l15;
          float v = acc[mf][nf][i] + bias;
          int b = n >> 11, m = n & 2047;
          Yf[((size_t)b * 256 + o) * 8192 + out_off + m] = v;
        }
      }
  }
}

// ---------------------------------------------------------------------------
// FRONT kernel (r18-VERIFIED): knn [0,2048) + cvtT [2048,4096) +
// wcvt [4096,7383). knn: 2 queries/wave ILP (verified r12/r15/r18);
// r19's 4-chain rescan split regressed (issue-bound, not latency-bound)
// and is reverted.
// ---------------------------------------------------------------------------
__global__ __launch_bounds__(256)
void front_k(const float* __restrict__ xyz, int* __restrict__ ids,
             const float* __restrict__ wp1, const float* __restrict__ bp1,
             unsigned short* __restrict__ t1,
             const float* __restrict__ fq, const float* __restrict__ fk,
             unsigned short* __restrict__ xqb, unsigned short* __restrict__ xkb,
             const float* __restrict__ w1, const float* __restrict__ w2,
             const float* __restrict__ wres, const float* __restrict__ wq,
             const float* __restrict__ wk, const float* __restrict__ wv,
             const float* __restrict__ wo, const float* __restrict__ wr,
             const float* __restrict__ wa1, const float* __restrict__ wa2,
             const float* __restrict__ wp2,
             const float* __restrict__ bo, const float* __restrict__ br,
             const float* __restrict__ b2, const float* __restrict__ bres,
             const float* __restrict__ bq, const float* __restrict__ bk,
             const float* __restrict__ bv, const float* __restrict__ ba2,
             unsigned short* __restrict__ wreg, float* __restrict__ bsum)
{
  __shared__ float smem[6528];   // 25.5 KB union: knn(sx,sy,sz,wp1,bp1,qid) / cvtT(sT)
  const int id = blockIdx.x;
  const int t  = threadIdx.x;

  if (id < 2048) {
    // ---------------- knn branch (2 queries/wave ILP, verified) ----------------
    float* sx = smem;
    float* sy = smem + 2048;
    float* sz = smem + 4096;
    float* s_wp1 = smem + 6144;            // 192
    float* s_bp1 = smem + 6336;            // 64
    int*   s_qid = (int*)(smem + 6400);    // 128 ints
    const int b  = id >> 8;
    const int mg = id & 255;
    const float* xb = xyz + (size_t)b * 2048 * 3;
    for (int i = t; i < 2048; i += 256) {
      float x = xb[3 * i], y = xb[3 * i + 1], z = xb[3 * i + 2];
      sx[i] = x; sy[i] = y; sz[i] = z;
    }
    if (t < 192) s_wp1[t] = wp1[t];
    if (t < 64)  s_bp1[t] = bp1[t];
    __syncthreads();
    const int wave = t >> 6, lane = t & 63;
    const int m0 = mg * 8 + wave * 2;
    const int m1 = m0 + 1;
    const float xm0 = sx[m0], ym0 = sy[m0], zm0 = sz[m0];
    const float xm1 = sx[m1], ym1 = sy[m1], zm1 = sz[m1];
    const float sq0 = xm0 * xm0 + ym0 * ym0 + zm0 * zm0;
    const float sq1 = xm1 * xm1 + ym1 * ym1 + zm1 * zm1;

    float d0[32], d1[32];
    #pragma unroll
    for (int j = 0; j < 32; ++j) {
      int nn = lane + 64 * j;
      float px = sx[nn], py = sy[nn], pz = sz[nn];
      float ps = px * px + py * py + pz * pz;
      d0[j] = sq0 + ps - 2.f * (px * xm0 + py * ym0 + pz * zm0);
      d1[j] = sq1 + ps - 2.f * (px * xm1 + py * ym1 + pz * zm1);
    }
    int* outp0 = ids + ((size_t)b * 2048 + m0) * 16;
    int* outp1 = ids + ((size_t)b * 2048 + m1) * 16;

    for (int it = 0; it < 16; ++it) {
      float bd0 = 3.4e38f; int bn0 = 0x7fffffff;
      float bd1 = 3.4e38f; int bn1 = 0x7fffffff;
      #pragma unroll
      for (int j = 0; j < 32; ++j) {
        int nn = lane + 64 * j;
        if (d0[j] < bd0) { bd0 = d0[j]; bn0 = nn; }
        if (d1[j] < bd1) { bd1 = d1[j]; bn1 = nn; }
      }
      #pragma unroll
      for (int off = 32; off > 0; off >>= 1) {
        float od0 = __shfl_xor(bd0, off, 64);
        int   on0 = __shfl_xor(bn0, off, 64);
        float od1 = __shfl_xor(bd1, off, 64);
        int   on1 = __shfl_xor(bn1, off, 64);
        if (od0 < bd0 || (od0 == bd0 && on0 < bn0)) { bd0 = od0; bn0 = on0; }
        if (od1 < bd1 || (od1 == bd1 && on1 < bn1)) { bd1 = od1; bn1 = on1; }
      }
      if ((bn0 & 63) == lane) {
        #pragma unroll
        for (int j = 0; j < 32; ++j) if (j == (bn0 >> 6)) d0[j] = 3.4e38f;
      }
      if ((bn1 & 63) == lane) {
        #pragma unroll
        for (int j = 0; j < 32; ++j) if (j == (bn1 >> 6)) d1[j] = 3.4e38f;
      }
      if (lane == 0) {
        outp0[it] = bn0; s_qid[wave * 32 + it] = bn0;
        outp1[it] = bn1; s_qid[wave * 32 + 16 + it] = bn1;
      }
    }

    float w0 = s_wp1[lane * 3 + 0], w1v = s_wp1[lane * 3 + 1], w2v = s_wp1[lane * 3 + 2];
    float bb = s_bp1[lane];
    {
      unsigned short* t1p = t1 + (((size_t)b * 2048 + m0) * 16) * 64;
      #pragma unroll
      for (int nb = 0; nb < 16; ++nb) {
        int idn = s_qid[wave * 32 + nb];
        float dx = sx[idn] - xm0, dy = sy[idn] - ym0, dz = sz[idn] - zm0;
        float v = fmaxf(w0 * dx + w1v * dy + w2v * dz + bb, 0.f);
        t1p[nb * 64 + lane] = f2bf(v);
      }
    }
    {
      unsigned short* t1p = t1 + (((size_t)b * 2048 + m1) * 16) * 64;
      #pragma unroll
      for (int nb = 0; nb < 16; ++nb) {
        int idn = s_qid[wave * 32 + 16 + nb];
        float dx = sx[idn] - xm1, dy = sy[idn] - ym1, dz = sz[idn] - zm1;
        float v = fmaxf(w0 * dx + w1v * dy + w2v * dz + bb, 0.f);
        t1p[nb * 64 + lane] = f2bf(v);
      }
    }
  } else if (id < 4096) {
    // ---------------- cvtT branch ----------------
    unsigned short* sT = (unsigned short*)smem;    // [64][68]
    const int lid = id - 2048;
    const int m0 = (lid & 31) * 64;
    const int c0 = ((lid >> 5) & 3) * 64;
    const int z  = lid >> 7;
    const int b  = z >> 1;
    const float* src = (z & 1) ? fk : fq;
    unsigned short* dst = (z & 1) ? xkb : xqb;
    #pragma unroll
    for (int it = 0; it < 16; ++it) {
      int idx = it * 256 + t;
      int c = idx >> 6, m = idx & 63;
      sT[m * 68 + c] = f2bf(src[((size_t)b * 256 + c0 + c) * 2048 + m0 + m]);
    }
    __syncthreads();
    #pragma unroll
    for (int it = 0; it < 8; ++it) {
      int idx = it * 256 + t;
      int n = idx >> 5, cw = idx & 31;
      unsigned int w = *reinterpret_cast<const unsigned int*>(&sT[n * 68 + cw * 2]);
      *reinterpret_cast<unsigned int*>(&dst[((size_t)b * 2048 + m0 + n) * 256 + c0 + cw * 2]) = w;
    }
  } else {
    // ---------------- weight-convert branch ----------------
    int i = (id - 4096) * 256 + t;
    if      (i < 131072) wreg[i] = f2bf(w1[i]);
    else if (i < 196608) wreg[i] = f2bf(w2[i - 131072]);
    else if (i < 327680) wreg[i] = f2bf(wres[i - 196608]);
    else if (i < 344064) wreg[i] = f2bf(wq[i - 327680]);
    else if (i < 360448) wreg[i] = f2bf(wk[i - 344064]);
    else if (i < 376832) wreg[i] = f2bf(wv[i - 360448]);
    else if (i < 442368) wreg[i] = f2bf(wo[i - 376832]);
    else if (i < 704512) wreg[i] = f2bf(wr[i - 442368]);
    else if (i < 770048) wreg[i] = f2bf(wa1[i - 704512]);
    else if (i < 835584) wreg[i] = f2bf(wa2[i - 770048] * SCL2);
    else if (i < 839680) wreg[i] = f2bf(wp2[i - 835584]);
    else {
      int j = i - 839680;
      if (j < 1024)      bsum[j] = bo[j] + br[j];
      else if (j < 1280) bsum[j] = b2[j - 1024] + bres[j - 1024];
      else if (j < 1472) {
        int j2 = j - 1280, zz = j2 >> 6, o = j2 & 63;
        bsum[j] = (zz == 0) ? bq[o] : (zz == 1) ? bk[o] : bv[o];
      }
      else if (j < 1728) bsum[j] = ba2[j - 1472] * SCL2;
    }
  }
}

// ---------------------------------------------------------------------------
// prep2: gather + assemble a0 = q - k_nbr + pos, vp = v_nbr + pos (bf16)
// ---------------------------------------------------------------------------
__global__ __launch_bounds__(256)
void prep2_k(const unsigned short* __restrict__ qb, const unsigned short* __restrict__ kb,
             const unsigned short* __restrict__ vb, const int* __restrict__ idsp,
             const unsigned short* __restrict__ posb,
             unsigned short* __restrict__ a0g, unsigned short* __restrict__ vpg)
{
  const int n = blockIdx.x;
  const int b = n >> 11;
  const int t = threadIdx.x;
  __shared__ int s_id[16];
  if (t < 16) s_id[t] = idsp[(size_t)n * 16 + t];
  __syncthreads();
  const int k  = t >> 4;
  const int c0 = (t & 15) * 4;
  const int nb = s_id[k];
  size_t colb = ((size_t)n * 16 + k) * 64 + c0;
  ushort4 q4 = *reinterpret_cast<const ushort4*>(qb + (size_t)n * 64 + c0);
  ushort4 k4 = *reinterpret_cast<const ushort4*>(kb + ((size_t)b * 2048 + nb) * 64 + c0);
  ushort4 v4 = *reinterpret_cast<const ushort4*>(vb + ((size_t)b * 2048 + nb) * 64 + c0);
  ushort4 p4 = *reinterpret_cast<const ushort4*>(posb + colb);
  float p0 = bf2f(p4.x), p1 = bf2f(p4.y), p2 = bf2f(p4.z), p3 = bf2f(p4.w);
  ushort4 av, wv;
  av.x = f2bf(bf2f(q4.x) - bf2f(k4.x) + p0);
  av.y = f2bf(bf2f(q4.y) - bf2f(k4.y) + p1);
  av.z = f2bf(bf2f(q4.z) - bf2f(k4.z) + p2);
  av.w = f2bf(bf2f(q4.w) - bf2f(k4.w) + p3);
  wv.x = f2bf(bf2f(v4.x) + p0);
  wv.y = f2bf(bf2f(v4.y) + p1);
  wv.z = f2bf(bf2f(v4.z) + p2);
  wv.w = f2bf(bf2f(v4.w) + p3);
  *reinterpret_cast<ushort4*>(a0g + colb) = av;
  *reinterpret_cast<ushort4*>(vpg + colb) = wv;
}

// ---------------------------------------------------------------------------
// MFMA attention v9 (r15/r17/r18-verified): XCD swizzle, W-in-LDS, VALU diet.
// ---------------------------------------------------------------------------
__global__ __launch_bounds__(256)
void attn_mfma_k(const unsigned short* __restrict__ a0g,
                 const unsigned short* __restrict__ vpg,
                 const unsigned short* __restrict__ w1bf,
                 const unsigned short* __restrict__ w2bf,
                 const float* __restrict__ ba1, const float* __restrict__ ba2s,
                 unsigned short* __restrict__ fb)
{
  const int bid  = blockIdx.x;
  const int up   = (bid >> 3) & 3;
  const int xblk = ((bid >> 5) << 3) + (bid & 7);
  const int wid  = threadIdx.x >> 6;
  const int lane = threadIdx.x & 63;
  const int l15  = lane & 15;
  const int lg   = lane >> 4;
  const int m0   = xblk * 256 + wid * 64;

  __shared__ unsigned short sW1[16384];
  __shared__ unsigned short sW2[16384];

  const unsigned short* W1 = w1bf + up * 16384;
  const unsigned short* W2 = w2bf + up * 16384;
  const float* B1 = ba1 + up * 256;
  const float* B2 = ba2s + up * 64;

  #pragma unroll
  for (int it = 0; it < 8; ++it) {
    int idx = it * 256 + threadIdx.x;
    int r = idx >> 3;
    int e = ((idx & 7) * 8) ^ ((r & 7) << 3);
    gload16(W1 + r * 64 + e, sW1 + idx * 8);
  }
  #pragma unroll
  for (int it = 0; it < 8; ++it) {
    int idx = it * 256 + threadIdx.x;
    int r = idx >> 3;
    int e = ((idx & 7) * 8) ^ ((r & 7) << 3);
    gload16(W2 + r * 64 + e, sW2 + idx * 8);
  }

  bfrag bf[4][2];
  #pragma unroll
  for (int nfc = 0; nfc < 4; ++nfc)
    #pragma unroll
    for (int kf = 0; kf < 2; ++kf)
      bf[nfc][kf] = *reinterpret_cast<const bfrag*>(
          a0g + (size_t)(m0 + nfc * 16 + l15) * 64 + kf * 32 + lg * 8);

  ffrag acc2[4][4];
  #pragma unroll
  for (int mf = 0; mf < 4; ++mf)
    #pragma unroll
    for (int nf = 0; nf < 4; ++nf)
      acc2[mf][nf] = (ffrag){0.f, 0.f, 0.f, 0.f};

  __syncthreads();

  const int orow_base = ((l15 >> 2) << 3) + (l15 & 3);

  for (int oc = 0; oc < 8; ++oc) {
    bfrag w1p[2][2];
    #pragma unroll
    for (int p = 0; p < 2; ++p)
      #pragma unroll
      for (int kf = 0; kf < 2; ++kf) {
        int r = oc * 32 + orow_base + 4 * p;
        int off = (kf * 32 + lg * 8) ^ ((r & 7) << 3);
        w1p[p][kf] = *reinterpret_cast<const bfrag*>(sW1 + r * 64 + off);
      }
    float4 b1q[2];
    #pragma unroll
    for (int p = 0; p < 2; ++p)
      b1q[p] = *reinterpret_cast<const float4*>(B1 + oc * 32 + lg * 8 + 4 * p);

    ffrag acc1[2][4];
    #pragma unroll
    for (int p = 0; p < 2; ++p)
      #pragma unroll
      for (int nfc = 0; nfc < 4; ++nfc)
        acc1[p][nfc] = (ffrag){b1q[p].x, b1q[p].y, b1q[p].z, b1q[p].w};
    #pragma unroll
    for (int kf = 0; kf < 2; ++kf)
      #pragma unroll
      for (int p = 0; p < 2; ++p)
        #pragma unroll
        for (int nfc = 0; nfc < 4; ++nfc)
          acc1[p][nfc] = __builtin_amdgcn_mfma_f32_16x16x32_bf16(
              w1p[p][kf], bf[nfc][kf], acc1[p][nfc], 0, 0, 0);

    bfrag w2t[4];
    #pragma unroll
    for (int nfd = 0; nfd < 4; ++nfd) {
      int dt = nfd * 16 + l15;
      int sr = dt * 4 + (oc >> 1);
      int off = ((oc & 1) * 32 + lg * 8) ^ ((sr & 7) << 3);
      w2t[nfd] = *reinterpret_cast<const bfrag*>(sW2 + sr * 64 + off);
    }

    #pragma unroll
    for (int nfc = 0; nfc < 4; ++nfc) {
      union { unsigned int u[4]; bfrag v; } cv;
      cv.u[0] = cvtpk(fmaxf(acc1[0][nfc][0], 0.f), fmaxf(acc1[0][nfc][1], 0.f));
      cv.u[1] = cvtpk(fmaxf(acc1[0][nfc][2], 0.f), fmaxf(acc1[0][nfc][3], 0.f));
      cv.u[2] = cvtpk(fmaxf(acc1[1][nfc][0], 0.f), fmaxf(acc1[1][nfc][1], 0.f));
      cv.u[3] = cvtpk(fmaxf(acc1[1][nfc][2], 0.f), fmaxf(acc1[1][nfc][3], 0.f));
      #pragma unroll
      for (int nfd = 0; nfd < 4; ++nfd)
        acc2[nfc][nfd] = __builtin_amdgcn_mfma_f32_16x16x32_bf16(
            cv.v, w2t[nfd], acc2[nfc][nfd], 0, 0, 0);
    }
  }

  #pragma unroll
  for (int mf = 0; mf < 4; ++mf) {
    float fsel = 0.f;
    #pragma unroll
    for (int nf = 0; nf < 4; ++nf) {
      float b2v = B2[nf * 16 + l15];
      float e[4], s = 0.f;
      #pragma unroll
      for (int i = 0; i < 4; ++i) { e[i] = fexp2(acc2[mf][nf][i] + b2v); s += e[i]; }
      s += __shfl_xor(s, 16, 64);
      s += __shfl_xor(s, 32, 64);
      float inv = frcp(s);
      float fp = 0.f;
      #pragma unroll
      for (int i = 0; i < 4; ++i) {
        int col = m0 + mf * 16 + lg * 4 + i;
        float vpv = bf2f(vpg[(size_t)col * 64 + nf * 16 + l15]);
        fp = fmaf(e[i] * inv, vpv, fp);
      }
      fp += __shfl_xor(fp, 16, 64);
      fp += __shfl_xor(fp, 32, 64);
      if (lg == nf) fsel = fp;
    }
    int pt = xblk * 16 + wid * 4 + mf;
    fb[((size_t)up * NPT + pt) * 64 + lane] = f2bf(fsel);
  }
}

// ---------------------------------------------------------------------------
extern "C" void kernel_launch(void* const* d_in, const int* in_sizes, int n_in,
                              void* d_out, int out_size, void* d_ws, size_t ws_size,
                              hipStream_t stream)
{
  const float* fq   = (const float*)d_in[0];
  const float* fk   = (const float*)d_in[1];
  const float* xyz  = (const float*)d_in[2];
  const float* w1   = (const float*)d_in[3];
  const float* b1   = (const float*)d_in[4];
  const float* w2   = (const float*)d_in[5];
  const float* b2   = (const float*)d_in[6];
  const float* wres = (const float*)d_in[7];
  const float* bres = (const float*)d_in[8];
  const float* wq   = (const float*)d_in[9];
  const float* bq   = (const float*)d_in[10];
  const float* wk   = (const float*)d_in[11];
  const float* bk   = (const float*)d_in[12];
  const float* wv   = (const float*)d_in[13];
  const float* bv   = (const float*)d_in[14];
  const float* wp1  = (const float*)d_in[15];
  const float* bp1  = (const float*)d_in[16];
  const float* wp2  = (const float*)d_in[17];
  const float* bp2  = (const float*)d_in[18];
  const float* wa1  = (const float*)d_in[19];
  const float* ba1  = (const float*)d_in[20];
  const float* wa2  = (const float*)d_in[21];
  const float* ba2  = (const float*)d_in[22];
  const float* wo   = (const float*)d_in[23];
  const float* bo   = (const float*)d_in[24];
  const float* wr   = (const float*)d_in[25];
  const float* br   = (const float*)d_in[26];
  float* out = (float*)d_out;
  (void)in_sizes; (void)n_in; (void)out_size; (void)ws_size;

  unsigned short* u    = (unsigned short*)d_ws;
  unsigned short* wreg = u;                        //   839,680
  unsigned short* xqb  = wreg + 839680;            // 4,194,304
  unsigned short* xkb  = xqb  + 4194304;
  unsigned short* ftsb = xkb  + 4194304;
  unsigned short* h1b  = ftsb + 4194304;           // reused as fbb
  unsigned short* a0g  = h1b  + 4194304;           // 16,777,216 (aliases t1)
  unsigned short* vpg  = a0g  + 16777216;          // 16,777,216 (aliases posb)
  unsigned short* qb   = vpg  + 16777216;          // 1,048,576
  unsigned short* kb   = qb   + 1048576;
  unsigned short* vb   = kb   + 1048576;
  int*   ids  = (int*)(vb + 1048576);              // 262,144 ints
  float* bsum = (float*)(ids + 262144);            // 1,728 floats

  unsigned short* w1b   = wreg;
  unsigned short* w2b   = wreg + 131072;
  unsigned short* wresb = wreg + 196608;
  unsigned short* wqb   = wreg + 327680;
  unsigned short* wrb   = wreg + 442368;
  unsigned short* wob   = wreg + 376832;
  unsigned short* wa1b  = wreg + 704512;
  unsigned short* wa2b  = wreg + 770048;
  unsigned short* wp2b  = wreg + 835584;
  unsigned short* t1    = a0g;    // alias: t1 dead before a0g written
  unsigned short* posb  = vpg;    // alias: consumed in place by prep2
  unsigned short* fbb   = h1b;
  const int BIG = 1 << 30;

  dim3 blk(256);

  // fused front: knn (blocks 0..2047) + cvtT (2048..4095) + wcvt (4096..7382)
  front_k<<<dim3(7383), blk, 0, stream>>>(
      xyz, ids, wp1, bp1, t1,
      fq, fk, xqb, xkb,
      w1, w2, wres, wq, wk, wv, wo, wr, wa1, wa2, wp2,
      bo, br, b2, bres, bq, bk, bv, ba2, wreg, bsum);

  // h1 = relu(w1 @ [fq;fk] + b1)  -> bf16 [n][256]
  bgemm_k<0, true, false><<<dim3(128, 4), blk, 0, stream>>>(
      xqb, xkb, xkb, 256, BIG, 256, 256, 256,
      w1b, w1b, BIG, 512, 512, b1, h1b, 512, 256, 0, 0, 0, 0, 0, 0, 0);
  // ftsv = [w2|wres] @ [h1;fq;fk] + (b2+bres) -> bf16 [n][256]
  bgemm_k<0, false, false><<<dim3(128, 4), blk, 0, stream>>>(
      h1b, xqb, xkb, 256, 512, 256, 256, 256,
      w2b, wresb, 256, 256, 512, bsum + 1024, ftsb, 768, 256, 0, 0, 0, 0, 0, 0, 0);
  // q, k, v projections fused: z = 0,1,2 over {xqb,xkb,ftsb} x {wq,wk,wv}
  bgemm_k<0, false, false><<<dim3(128, 1, 3), blk, 0, stream>>>(
      xqb, xqb, xqb, BIG, BIG, 256, 256, 256,
      wqb, wqb, BIG, 256, 256, bsum + 1280, qb, 256, 64, 0,
      4194304, 16384, 16384, 64, 0, 1048576);

  // pos = wp2 @ t1 + bp2  -> bf16 [col][64]   (N = 262144 cols)
  bgemm_k<0, false, false><<<dim3(2048, 1), blk, 0, stream>>>(
      t1, t1, t1, BIG, BIG, 64, 64, 64,
      wp2b, wp2b, BIG, 64, 64, bp2, posb, 64, 64, 0, 0, 0, 0, 0, 0, 0);

  prep2_k<<<dim3(NPT), blk, 0, stream>>>(qb, kb, vb, ids, posb, a0g, vpg);
  attn_mfma_k<<<dim3(4096), blk, 0, stream>>>(a0g, vpg, wa1b, wa2b, ba1, bsum + 1472, fbb);

  // out[:, :, i*2048:(i+1)*2048] = [wo_i|wr_i] @ [f_i; ftsv] + (bo_i+br_i)
  bgemm_k<2, false, true><<<dim3(128, 4, UP_), blk, 0, stream>>>(
      fbb, ftsb, ftsb, 64, BIG, 64, 256, 256,
      wob, wrb, 64, 64, 256,
      bsum, out, 320, 256, 0,
      1048576, 16384, 65536, 256, 2048, 0);
}